// Round 6
// baseline (32540.573 us; speedup 1.0000x reference)
//
#include <hip/hip_runtime.h>
#include <cstdint>

// ============================================================================
// STModel forward on MI355X — BISECTION ROUND.
// Established: inputs f32 (npz 249MB), output f32 (round-0 finite absmax with
// f32 writes proves f32 readback; bf16 would NaN). Round-0 absmax 4.03 with
// correct I/O => compute bug. All op-level math audited clean => suspect is
// the MFMA GEMM machinery. This round: plain smem VALU GEMM (f32 acc, no
// global_load_lds, no fragment layouts). Everything else unchanged.
// WS lean 140.5 MB: wt 8.4 | x(f32) 37.7 | y 18.9 | big 75.5
// ============================================================================

typedef unsigned short u16;

#define PI_F 3.14159265358979323846f

__device__ __forceinline__ u16 f2bf(float x) {
  unsigned u = __builtin_bit_cast(unsigned, x);
  u += 0x7fffu + ((u >> 16) & 1u);
  return (u16)(u >> 16);
}
__device__ __forceinline__ float bf2f(u16 h) {
  unsigned u = ((unsigned)h) << 16;
  return __builtin_bit_cast(float, u);
}

// ---- weight convert+transpose: W (K,N) f32 -> Wt (N,K) bf16 (one layer) ----
__global__ __launch_bounds__(256) void wconv_kernel(const float* __restrict__ W,
    u16* __restrict__ Wt, int K, int N) {
  __shared__ float tile[32][33];
  int n0 = blockIdx.x * 32, k0 = blockIdx.y * 32;
  int tx = threadIdx.x & 31, ty = threadIdx.x >> 5;
#pragma unroll
  for (int i = 0; i < 4; i++)
    tile[ty + i * 8][tx] = W[(size_t)(k0 + ty + i * 8) * N + n0 + tx];
  __syncthreads();
#pragma unroll
  for (int i = 0; i < 4; i++)
    Wt[(size_t)(n0 + ty + i * 8) * K + k0 + tx] = f2bf(tile[tx][ty + i * 8]);
}

// ---- embedding ----
__global__ __launch_bounds__(256) void embed_kernel(const float* __restrict__ tok,
    const float* __restrict__ tim, const float* __restrict__ pos,
    const int* __restrict__ seq, float* __restrict__ x) {
  int row = blockIdx.x;
  int n = row % 18;
  int v = seq[row];
  int c = threadIdx.x;
  float4 a = ((const float4*)(tok + (size_t)v * 1024))[c];
  float4 p = ((const float4*)(pos + (size_t)(n % 9) * 1024))[c];
  float4 t = ((const float4*)(tim + (size_t)(n / 9) * 1024))[c];
  a.x += p.x + t.x; a.y += p.y + t.y; a.z += p.z + t.z; a.w += p.w + t.w;
  ((float4*)(x + (size_t)row * 1024))[c] = a;
}

// ---- LayerNorm row (1024) f32 -> bf16 ----
__global__ __launch_bounds__(256) void ln_kernel(const float* __restrict__ x,
    const float* __restrict__ g, const float* __restrict__ b,
    u16* __restrict__ y) {
  int row = blockIdx.x;
  int tid = threadIdx.x;
  float4 v = ((const float4*)(x + (size_t)row * 1024))[tid];
  float s = v.x + v.y + v.z + v.w;
  float s2 = v.x * v.x + v.y * v.y + v.z * v.z + v.w * v.w;
#pragma unroll
  for (int o = 32; o > 0; o >>= 1) { s += __shfl_down(s, o); s2 += __shfl_down(s2, o); }
  __shared__ float ps[4], ps2[4];
  if ((tid & 63) == 0) { ps[tid >> 6] = s; ps2[tid >> 6] = s2; }
  __syncthreads();
  s = ps[0] + ps[1] + ps[2] + ps[3];
  s2 = ps2[0] + ps2[1] + ps2[2] + ps2[3];
  float m = s * (1.f / 1024.f);
  float inv = rsqrtf(s2 * (1.f / 1024.f) - m * m + 1e-5f);
  float4 gg = ((const float4*)g)[tid];
  float4 bb = ((const float4*)b)[tid];
  ushort4 o4;
  o4.x = f2bf((v.x - m) * inv * gg.x + bb.x);
  o4.y = f2bf((v.y - m) * inv * gg.y + bb.y);
  o4.z = f2bf((v.z - m) * inv * gg.z + bb.z);
  o4.w = f2bf((v.w - m) * inv * gg.w + bb.w);
  ((ushort4*)(y + (size_t)row * 1024))[tid] = o4;
}

// ---- plain smem GEMM: C(MxN) = A(MxK,bf16) * Bt(NxK,bf16)^T ----
// 64x64 tile, 256 threads (16x16), 4x4 per thread, f32 accumulate.
// EP=0: store bf16. EP=1: Cres += acc + bias. EP=2: bias+GELU->bf16.
template <int EP>
__global__ __launch_bounds__(256) void sgemm_kernel(
    const u16* __restrict__ A,
    const u16* __restrict__ Bt,
    const float* __restrict__ bias,
    u16* __restrict__ Cbf,
    float* __restrict__ Cres,
    int M, int N, int K) {
  __shared__ float As[64][36];
  __shared__ float Bs[64][36];
  int tid = threadIdx.x;
  int tx = tid & 15, ty = tid >> 4;
  int bm = blockIdx.y, bn = blockIdx.x;
  float acc[4][4] = {{0.f}};
  for (int kt = 0; kt < K; kt += 32) {
    __syncthreads();   // protect previous iteration's smem reads
#pragma unroll
    for (int e = 0; e < 8; e++) {
      int idx = tid * 8 + e;          // 0..2047
      int r = idx >> 5, c = idx & 31;
      As[r][c] = bf2f(A[(size_t)(bm * 64 + r) * K + kt + c]);
      Bs[r][c] = bf2f(Bt[(size_t)(bn * 64 + r) * K + kt + c]);
    }
    __syncthreads();
#pragma unroll
    for (int k0 = 0; k0 < 32; k0 += 4) {
      float4 a4[4], b4[4];
#pragma unroll
      for (int i = 0; i < 4; i++) a4[i] = *(const float4*)&As[ty * 4 + i][k0];
#pragma unroll
      for (int j = 0; j < 4; j++) b4[j] = *(const float4*)&Bs[tx * 4 + j][k0];
#pragma unroll
      for (int i = 0; i < 4; i++)
#pragma unroll
        for (int j = 0; j < 4; j++)
          acc[i][j] += a4[i].x * b4[j].x + a4[i].y * b4[j].y
                     + a4[i].z * b4[j].z + a4[i].w * b4[j].w;
    }
  }
  int r0 = bm * 64 + ty * 4, c0 = bn * 64 + tx * 4;
#pragma unroll
  for (int i = 0; i < 4; i++) {
#pragma unroll
    for (int j = 0; j < 4; j++) {
      int row = r0 + i, col = c0 + j;
      float v = acc[i][j];
      if (EP == 0) {
        Cbf[(size_t)row * N + col] = f2bf(v);
      } else if (EP == 1) {
        size_t o = (size_t)row * N + col;
        Cres[o] += v + bias[col];
      } else {
        float t = v + bias[col];
        float ge = 0.5f * t * (1.f + erff(t * 0.70710678118f));
        Cbf[(size_t)row * N + col] = f2bf(ge);
      }
    }
  }
}

// ---- spatial RoPE in place on q,k ----
__global__ __launch_bounds__(256) void rope_sp_kernel(u16* __restrict__ qkv) {
  int idx = blockIdx.x * 256 + threadIdx.x;
  if (idx >= 9216 * 1024) return;
  int pair = idx & 31;
  int h = (idx >> 5) & 15;
  int qk = (idx >> 9) & 1;
  int tok = idx >> 10;
  int n = tok % 18;
  int p9 = n % 9;
  float coef = (pair < 16) ? (float)(p9 / 3 - 1) : (float)(p9 % 3 - 1);
  int pj = (pair < 16) ? pair : pair - 16;
  float ang = coef * (PI_F + (float)pj * (4.f * PI_F / 15.f));
  float sn, cs;
  sincosf(ang, &sn, &cs);
  unsigned* ptr = (unsigned*)(qkv + (size_t)tok * 3072 + qk * 1024 + h * 64 + pair * 2);
  unsigned u = *ptr;
  float x1 = bf2f((u16)(u & 0xffff));
  float x2 = bf2f((u16)(u >> 16));
  float r1 = x1 * cs - x2 * sn;
  float r2 = x1 * sn + x2 * cs;
  *ptr = (unsigned)f2bf(r1) | ((unsigned)f2bf(r2) << 16);
}

// ---- temporal RoPE in place ----
__global__ __launch_bounds__(256) void rope_tm_kernel(u16* __restrict__ qkv) {
  int idx = blockIdx.x * 256 + threadIdx.x;
  if (idx >= 9216 * 1024) return;
  int pair = idx & 31;
  int h = (idx >> 5) & 15;
  int qk = (idx >> 9) & 1;
  int tok = idx >> 10;
  int t = (tok % 18) / 9;
  float ang = (float)t * exp2f(-(float)pair * 0.41524101f);
  float sn, cs;
  sincosf(ang, &sn, &cs);
  unsigned* ptr = (unsigned*)(qkv + (size_t)tok * 3072 + qk * 1024 + h * 64 + pair * 2);
  unsigned u = *ptr;
  float x1 = bf2f((u16)(u & 0xffff));
  float x2 = bf2f((u16)(u >> 16));
  float r1 = x1 * cs - x2 * sn;
  float r2 = x1 * sn + x2 * cs;
  *ptr = (unsigned)f2bf(r1) | ((unsigned)f2bf(r2) << 16);
}

#define LOAD8(dst, ptr, c)                          \
  {                                                 \
    uint4 u = ((const uint4*)(ptr))[c];             \
    unsigned w0 = u.x, w1 = u.y, w2 = u.z, w3 = u.w;\
    dst[(c)*8 + 0] = bf2f((u16)(w0 & 0xffff));      \
    dst[(c)*8 + 1] = bf2f((u16)(w0 >> 16));         \
    dst[(c)*8 + 2] = bf2f((u16)(w1 & 0xffff));      \
    dst[(c)*8 + 3] = bf2f((u16)(w1 >> 16));         \
    dst[(c)*8 + 4] = bf2f((u16)(w2 & 0xffff));      \
    dst[(c)*8 + 5] = bf2f((u16)(w2 >> 16));         \
    dst[(c)*8 + 6] = bf2f((u16)(w3 & 0xffff));      \
    dst[(c)*8 + 7] = bf2f((u16)(w3 >> 16));         \
  }

// ---- spatial attention: one thread per (b,t,h,query), 9 keys ----
__global__ __launch_bounds__(256) void attn_sp_kernel(const u16* __restrict__ qkv,
    u16* __restrict__ out) {
  int idx = blockIdx.x * 256 + threadIdx.x;
  if (idx >= 512 * 2 * 16 * 9) return;
  int qi = idx % 9;
  int h = (idx / 9) & 15;
  int t = (idx / 144) & 1;
  int b = idx / 288;
  size_t tokbase = (size_t)b * 18 + t * 9;
  const u16* qp = qkv + (tokbase + qi) * 3072 + h * 64;
  float q[64];
#pragma unroll
  for (int c = 0; c < 8; c++) LOAD8(q, qp, c);
  float s[9];
  float mx = -1e30f;
#pragma unroll
  for (int j = 0; j < 9; j++) {
    const u16* kp = qkv + (tokbase + j) * 3072 + 1024 + h * 64;
    float kv[64];
#pragma unroll
    for (int c = 0; c < 8; c++) LOAD8(kv, kp, c);
    float a = 0.f;
#pragma unroll
    for (int d = 0; d < 64; d++) a += q[d] * kv[d];
    s[j] = a * 0.125f;
    mx = fmaxf(mx, s[j]);
  }
  float sum = 0.f;
#pragma unroll
  for (int j = 0; j < 9; j++) { s[j] = __expf(s[j] - mx); sum += s[j]; }
  float rs = 1.f / sum;
  float o[64];
#pragma unroll
  for (int d = 0; d < 64; d++) o[d] = 0.f;
#pragma unroll
  for (int j = 0; j < 9; j++) {
    float p = s[j] * rs;
    const u16* vp = qkv + (tokbase + j) * 3072 + 2048 + h * 64;
    float vv[64];
#pragma unroll
    for (int c = 0; c < 8; c++) LOAD8(vv, vp, c);
#pragma unroll
    for (int d = 0; d < 64; d++) o[d] += p * vv[d];
  }
  u16* op = out + (tokbase + qi) * 1024 + h * 64;
#pragma unroll
  for (int c = 0; c < 8; c++) {
    uint4 u;
    u.x = (unsigned)f2bf(o[c * 8 + 0]) | ((unsigned)f2bf(o[c * 8 + 1]) << 16);
    u.y = (unsigned)f2bf(o[c * 8 + 2]) | ((unsigned)f2bf(o[c * 8 + 3]) << 16);
    u.z = (unsigned)f2bf(o[c * 8 + 4]) | ((unsigned)f2bf(o[c * 8 + 5]) << 16);
    u.w = (unsigned)f2bf(o[c * 8 + 6]) | ((unsigned)f2bf(o[c * 8 + 7]) << 16);
    ((uint4*)op)[c] = u;
  }
}

// ---- temporal (causal, T=2) attention ----
__global__ __launch_bounds__(256) void attn_tm_kernel(const u16* __restrict__ qkv,
    u16* __restrict__ out) {
  int idx = blockIdx.x * 256 + threadIdx.x;
  if (idx >= 512 * 9 * 16 * 2) return;
  int t = idx & 1;
  int h = (idx >> 1) & 15;
  int p = (idx >> 5) % 9;
  int b = idx / 288;
  size_t tokq = (size_t)b * 18 + t * 9 + p;
  const u16* qp = qkv + tokq * 3072 + h * 64;
  float q[64];
#pragma unroll
  for (int c = 0; c < 8; c++) LOAD8(q, qp, c);
  float s[2] = {0.f, 0.f};
  for (int j = 0; j <= t; j++) {
    const u16* kp = qkv + ((size_t)b * 18 + j * 9 + p) * 3072 + 1024 + h * 64;
    float kv[64];
#pragma unroll
    for (int c = 0; c < 8; c++) LOAD8(kv, kp, c);
    float a = 0.f;
#pragma unroll
    for (int d = 0; d < 64; d++) a += q[d] * kv[d];
    s[j] = a * 0.125f;
  }
  float w0, w1;
  if (t == 0) { w0 = 1.f; w1 = 0.f; }
  else {
    float mx = fmaxf(s[0], s[1]);
    float e0 = __expf(s[0] - mx), e1 = __expf(s[1] - mx);
    float rs = 1.f / (e0 + e1);
    w0 = e0 * rs; w1 = e1 * rs;
  }
  float o[64];
#pragma unroll
  for (int d = 0; d < 64; d++) o[d] = 0.f;
  for (int j = 0; j <= t; j++) {
    float p2 = (j == 0) ? w0 : w1;
    const u16* vp = qkv + ((size_t)b * 18 + j * 9 + p) * 3072 + 2048 + h * 64;
    float vv[64];
#pragma unroll
    for (int c = 0; c < 8; c++) LOAD8(vv, vp, c);
#pragma unroll
    for (int d = 0; d < 64; d++) o[d] += p2 * vv[d];
  }
  u16* op = out + tokq * 1024 + h * 64;
#pragma unroll
  for (int c = 0; c < 8; c++) {
    uint4 u;
    u.x = (unsigned)f2bf(o[c * 8 + 0]) | ((unsigned)f2bf(o[c * 8 + 1]) << 16);
    u.y = (unsigned)f2bf(o[c * 8 + 2]) | ((unsigned)f2bf(o[c * 8 + 3]) << 16);
    u.z = (unsigned)f2bf(o[c * 8 + 4]) | ((unsigned)f2bf(o[c * 8 + 5]) << 16);
    u.w = (unsigned)f2bf(o[c * 8 + 6]) | ((unsigned)f2bf(o[c * 8 + 7]) << 16);
    ((uint4*)op)[c] = u;
  }
}

// ---- head: out(9216,84) f32 = x(9216,1024) @ head_w(1024,84) + head_b ----
__global__ __launch_bounds__(128) void head_kernel(const float* __restrict__ x,
    const float* __restrict__ hw, const float* __restrict__ hb,
    float* __restrict__ out) {
  __shared__ float xs[4][1024];
  int r0 = blockIdx.x * 4;
  int tid = threadIdx.x;
#pragma unroll
  for (int i = 0; i < 8; i++) {
    int e = i * 128 + tid;
    ((float4*)&xs[0][0])[e] = ((const float4*)(x + (size_t)r0 * 1024))[e];
  }
  __syncthreads();
  if (tid < 84) {
    float a0 = 0.f, a1 = 0.f, a2 = 0.f, a3 = 0.f;
#pragma unroll 8
    for (int d = 0; d < 1024; d++) {
      float w = hw[d * 84 + tid];
      a0 += xs[0][d] * w;
      a1 += xs[1][d] * w;
      a2 += xs[2][d] * w;
      a3 += xs[3][d] * w;
    }
    float bb = hb[tid];
    out[(size_t)(r0 + 0) * 84 + tid] = a0 + bb;
    out[(size_t)(r0 + 1) * 84 + tid] = a1 + bb;
    out[(size_t)(r0 + 2) * 84 + tid] = a2 + bb;
    out[(size_t)(r0 + 3) * 84 + tid] = a3 + bb;
  }
}

extern "C" void kernel_launch(void* const* d_in, const int* in_sizes, int n_in,
                              void* d_out, int out_size, void* d_ws, size_t ws_size,
                              hipStream_t stream) {
  const float* token_emb = (const float*)d_in[0];
  const float* time_emb  = (const float*)d_in[1];
  const float* pos2d     = (const float*)d_in[2];
  const float* ln1_g = (const float*)d_in[3];
  const float* ln1_b = (const float*)d_in[4];
  const float* ln2_g = (const float*)d_in[5];
  const float* ln2_b = (const float*)d_in[6];
  const float* sp_qkv   = (const float*)d_in[7];
  const float* sp_out_w = (const float*)d_in[8];
  const float* sp_out_b = (const float*)d_in[9];
  const float* tm_qkv   = (const float*)d_in[10];
  const float* tm_out_w = (const float*)d_in[11];
  const float* tm_out_b = (const float*)d_in[12];
  const float* mlp_ln_g = (const float*)d_in[13];
  const float* mlp_ln_b = (const float*)d_in[14];
  const float* mlp_w1 = (const float*)d_in[15];
  const float* mlp_b1 = (const float*)d_in[16];
  const float* mlp_w2 = (const float*)d_in[17];
  const float* mlp_b2 = (const float*)d_in[18];
  const float* head_w = (const float*)d_in[19];
  const float* head_b = (const float*)d_in[20];
  const int* seq    = (const int*)d_in[21];

  // ---- lean workspace: 140.5 MB total ----
  u16* wt = (u16*)d_ws;                                  // 4096*1024 bf16 (8.4 MB)
  float* x = (float*)(wt + (size_t)4096 * 1024);         // 37.7 MB
  u16* y = (u16*)(x + (size_t)9216 * 1024);              // 18.9 MB
  u16* big = y + (size_t)9216 * 1024;                    // 75.5 MB
  u16* qkvb = big;
  u16* attno = big + (size_t)9216 * 3072;
  u16* hbuf = big;   // overlays qkv+attno (dead by MLP phase)

  embed_kernel<<<9216, 256, 0, stream>>>(token_emb, time_emb, pos2d, seq, x);

  for (int i = 0; i < 4; i++) {
    // ---- spatial attention block ----
    ln_kernel<<<9216, 256, 0, stream>>>(x, ln1_g + i * 1024, ln1_b + i * 1024, y);
    wconv_kernel<<<dim3(96, 32), 256, 0, stream>>>(sp_qkv + (size_t)i * 1024 * 3072, wt, 1024, 3072);
    sgemm_kernel<0><<<dim3(48, 144), 256, 0, stream>>>(y, wt, nullptr, qkvb, nullptr, 9216, 3072, 1024);
    rope_sp_kernel<<<36864, 256, 0, stream>>>(qkvb);
    attn_sp_kernel<<<576, 256, 0, stream>>>(qkvb, attno);
    wconv_kernel<<<dim3(32, 32), 256, 0, stream>>>(sp_out_w + (size_t)i * 1024 * 1024, wt, 1024, 1024);
    sgemm_kernel<1><<<dim3(16, 144), 256, 0, stream>>>(attno, wt, sp_out_b + i * 1024, nullptr, x, 9216, 1024, 1024);
    // ---- temporal attention block ----
    ln_kernel<<<9216, 256, 0, stream>>>(x, ln2_g + i * 1024, ln2_b + i * 1024, y);
    wconv_kernel<<<dim3(96, 32), 256, 0, stream>>>(tm_qkv + (size_t)i * 1024 * 3072, wt, 1024, 3072);
    sgemm_kernel<0><<<dim3(48, 144), 256, 0, stream>>>(y, wt, nullptr, qkvb, nullptr, 9216, 3072, 1024);
    rope_tm_kernel<<<36864, 256, 0, stream>>>(qkvb);
    attn_tm_kernel<<<576, 256, 0, stream>>>(qkvb, attno);
    wconv_kernel<<<dim3(32, 32), 256, 0, stream>>>(tm_out_w + (size_t)i * 1024 * 1024, wt, 1024, 1024);
    sgemm_kernel<1><<<dim3(16, 144), 256, 0, stream>>>(attno, wt, tm_out_b + i * 1024, nullptr, x, 9216, 1024, 1024);
    // ---- MLP ----
    ln_kernel<<<9216, 256, 0, stream>>>(x, mlp_ln_g + i * 1024, mlp_ln_b + i * 1024, y);
    wconv_kernel<<<dim3(128, 32), 256, 0, stream>>>(mlp_w1 + (size_t)i * 1024 * 4096, wt, 1024, 4096);
    sgemm_kernel<2><<<dim3(64, 144), 256, 0, stream>>>(y, wt, mlp_b1 + i * 4096, hbuf, nullptr, 9216, 4096, 1024);
    wconv_kernel<<<dim3(32, 128), 256, 0, stream>>>(mlp_w2 + (size_t)i * 4096 * 1024, wt, 4096, 1024);
    sgemm_kernel<1><<<dim3(16, 144), 256, 0, stream>>>(hbuf, wt, mlp_b2 + i * 1024, nullptr, x, 9216, 1024, 4096);
  }

  head_kernel<<<2304, 128, 0, stream>>>(x, head_w, head_b, (float*)d_out);
}